// Round 2
// baseline (782.944 us; speedup 1.0000x reference)
//
#include <hip/hip_runtime.h>
#include <hip/hip_bf16.h>
#include <math.h>

#define S_LEN   2048
#define HIDDEN  2048
#define NHEADS  16
#define NKVH    4
#define HDIM    128

typedef short  short8  __attribute__((ext_vector_type(8)));
typedef float  floatx4 __attribute__((ext_vector_type(4)));
typedef __hip_bfloat16 bf16;

__device__ inline void async_copy16(const void* g, void* l) {
  __builtin_amdgcn_global_load_lds((__attribute__((address_space(1))) void*)(g),
                                   (__attribute__((address_space(3))) void*)(l),
                                   16, 0, 0);
}

__device__ inline unsigned short cvt1(float x) {
  bf16 t = __float2bfloat16(x);
  return *reinterpret_cast<unsigned short*>(&t);
}

// fp32 -> bf16, 8 elements per thread
__global__ __launch_bounds__(256) void cvt_f32_bf16(const float* __restrict__ src,
                                                    unsigned short* __restrict__ dst,
                                                    int n8) {
  const int i = blockIdx.x * 256 + threadIdx.x;
  if (i >= n8) return;
  const float4 a = reinterpret_cast<const float4*>(src)[i * 2];
  const float4 b = reinterpret_cast<const float4*>(src)[i * 2 + 1];
  unsigned short o[8] = {cvt1(a.x), cvt1(a.y), cvt1(a.z), cvt1(a.w),
                         cvt1(b.x), cvt1(b.y), cvt1(b.z), cvt1(b.w)};
  *reinterpret_cast<short8*>(dst + (size_t)i * 8) = *reinterpret_cast<short8*>(o);
}

// C[M,N] = A[M,K] * B[N,K]^T, bf16 in, fp32 accumulate.
// MODE 0: scatter epilogue -> qbuf [b,h,s,d], kbuf [b,kvh,s,d], vtbuf [b,kvh,d,s] (bf16)
// MODE 1: Cout[m*N + n] fp32 row-major
template<int MODE>
__global__ __launch_bounds__(256) void gemm_bt(const bf16* __restrict__ A,
                                               const bf16* __restrict__ B,
                                               int M, int N, int K,
                                               bf16* __restrict__ qbuf,
                                               bf16* __restrict__ kbuf,
                                               bf16* __restrict__ vtbuf,
                                               float* __restrict__ Cout)
{
  __shared__ unsigned short As[128 * 32];
  __shared__ unsigned short Bs[128 * 32];
  const int t    = threadIdx.x;
  const int w    = t >> 6;
  const int lane = t & 63;
  const int m16  = lane & 15;
  const int quad = lane >> 4;
  const int wm   = (w >> 1) * 64;
  const int wn   = (w & 1) * 64;
  const int bm   = blockIdx.y, bn = blockIdx.x;

  const floatx4 zf = {0.f, 0.f, 0.f, 0.f};
  floatx4 acc[4][4];
#pragma unroll
  for (int i = 0; i < 4; ++i)
#pragma unroll
    for (int j = 0; j < 4; ++j) acc[i][j] = zf;

  const bf16* gA = A + (size_t)(bm * 128 + (t >> 2)) * K + (t & 3) * 8;
  const bf16* gB = B + (size_t)(bn * 128 + (t >> 2)) * K + (t & 3) * 8;
  unsigned short* lA = &As[w * 512];
  unsigned short* lB = &Bs[w * 512];

  for (int k0 = 0; k0 < K; k0 += 32) {
    __syncthreads();
#pragma unroll
    for (int i = 0; i < 2; ++i) {
      async_copy16(gA + (size_t)(64 * i) * K + k0, lA + i * 2048);
      async_copy16(gB + (size_t)(64 * i) * K + k0, lB + i * 2048);
    }
    __builtin_amdgcn_s_waitcnt(0);
    __syncthreads();
    short8 af[4], bfr[4];
#pragma unroll
    for (int mi = 0; mi < 4; ++mi)
      af[mi] = *reinterpret_cast<const short8*>(&As[(wm + mi * 16 + m16) * 32 + quad * 8]);
#pragma unroll
    for (int ni = 0; ni < 4; ++ni)
      bfr[ni] = *reinterpret_cast<const short8*>(&Bs[(wn + ni * 16 + m16) * 32 + quad * 8]);
#pragma unroll
    for (int mi = 0; mi < 4; ++mi)
#pragma unroll
      for (int ni = 0; ni < 4; ++ni)
        acc[mi][ni] = __builtin_amdgcn_mfma_f32_16x16x32_bf16(af[mi], bfr[ni], acc[mi][ni], 0, 0, 0);
  }

#pragma unroll
  for (int mi = 0; mi < 4; ++mi)
#pragma unroll
    for (int ni = 0; ni < 4; ++ni) {
      const int row0 = bm * 128 + wm + mi * 16 + quad * 4;
      const int col  = bn * 128 + wn + ni * 16 + m16;
#pragma unroll
      for (int r = 0; r < 4; ++r) {
        const float v = acc[mi][ni][r];
        const int m = row0 + r;
        if (MODE == 0) {
          const int b = m >> 11, s = m & 2047;
          if (col < HIDDEN) {
            const int hh = col >> 7, d = col & 127;
            qbuf[(((size_t)(b * NHEADS + hh)) * S_LEN + s) * HDIM + d] = __float2bfloat16(v);
          } else if (col < HIDDEN + NKVH * HDIM) {
            const int nn = col - HIDDEN; const int hh = nn >> 7, d = nn & 127;
            kbuf[(((size_t)(b * NKVH + hh)) * S_LEN + s) * HDIM + d] = __float2bfloat16(v);
          } else {
            const int nn = col - HIDDEN - NKVH * HDIM; const int hh = nn >> 7, d = nn & 127;
            vtbuf[(((size_t)(b * NKVH + hh)) * HDIM + d) * S_LEN + s] = __float2bfloat16(v);
          }
        } else {
          Cout[(size_t)m * N + col] = v;
        }
      }
    }
}

// In-place RoPE on qbuf [B,NH,S,HD] and kbuf [B,NKV,S,HD]; pos == s (arange).
__global__ __launch_bounds__(256) void rope_kernel(bf16* __restrict__ qbuf,
                                                   bf16* __restrict__ kbuf)
{
  const int idx = blockIdx.x * 256 + threadIdx.x;
  const int QC = 2 * NHEADS * S_LEN * 64;  // 4,194,304
  bf16* base; int s, j;
  if (idx < QC) {
    j = idx & 63; const int tt = idx >> 6; s = tt & (S_LEN - 1);
    base = qbuf + (size_t)tt * HDIM;
  } else {
    const int k = idx - QC;
    j = k & 63; const int tt = k >> 6; s = tt & (S_LEN - 1);
    base = kbuf + (size_t)tt * HDIM;
  }
  const float inv = 1.0f / powf(10000.0f, (float)j * (1.0f / 64.0f));
  const float ang = (float)s * inv;
  const float c = cosf(ang), sn = sinf(ang);
  const float x0 = __bfloat162float(base[j]);
  const float x1 = __bfloat162float(base[j + 64]);
  base[j]      = __float2bfloat16(x0 * c - x1 * sn);
  base[j + 64] = __float2bfloat16(x1 * c + x0 * sn);
}

// Flash attention, causal, GQA. One wave = 16 q rows. No block barriers:
// K/V frags read straight from global (L1/L2 reuse), P via wave-private LDS.
__global__ __launch_bounds__(256) void attn_kernel(const bf16* __restrict__ qbuf,
                                                   const bf16* __restrict__ kbuf,
                                                   const bf16* __restrict__ vtbuf,
                                                   bf16* __restrict__ aout)
{
  __shared__ unsigned short Ps[4][16 * 40];
  const int t = threadIdx.x;
  const int w = t >> 6, lane = t & 63, m16 = lane & 15, quad = lane >> 4;
  const int q0 = blockIdx.x * 64 + w * 16;   // this wave's first q row
  const int h = blockIdx.y, b = blockIdx.z, kvh = h >> 2;

  const bf16* Qp = qbuf + (((size_t)(b * NHEADS + h)) * S_LEN + q0 + m16) * HDIM;
  short8 qf[4];
#pragma unroll
  for (int c = 0; c < 4; ++c)
    qf[c] = *reinterpret_cast<const short8*>(Qp + c * 32 + quad * 8);

  const bf16* Kp  = kbuf  + ((size_t)(b * NKVH + kvh)) * S_LEN * HDIM;
  const bf16* Vtp = vtbuf + ((size_t)(b * NKVH + kvh)) * HDIM * S_LEN;

  const floatx4 zf = {0.f, 0.f, 0.f, 0.f};
  floatx4 oacc[8];
#pragma unroll
  for (int i = 0; i < 8; ++i) oacc[i] = zf;
  float mrow[4], lrow[4];
#pragma unroll
  for (int r = 0; r < 4; ++r) { mrow[r] = -INFINITY; lrow[r] = 0.f; }

  const int myrow = q0 + quad * 4;
  const float scale = 0.08838834764831845f;  // 1/sqrt(128)
  unsigned short* Pw = &Ps[w][0];

  for (int ks = 0; ks < q0 + 16; ks += 32) {
    floatx4 s0 = zf, s1 = zf;
#pragma unroll
    for (int c = 0; c < 4; ++c) {
      short8 kf0 = *reinterpret_cast<const short8*>(Kp + (size_t)(ks + m16) * HDIM + c * 32 + quad * 8);
      short8 kf1 = *reinterpret_cast<const short8*>(Kp + (size_t)(ks + 16 + m16) * HDIM + c * 32 + quad * 8);
      s0 = __builtin_amdgcn_mfma_f32_16x16x32_bf16(qf[c], kf0, s0, 0, 0, 0);
      s1 = __builtin_amdgcn_mfma_f32_16x16x32_bf16(qf[c], kf1, s1, 0, 0, 0);
    }
    float p0[4], p1[4], tmax[4];
#pragma unroll
    for (int r = 0; r < 4; ++r) {
      const int row = myrow + r;
      const float v0 = (ks + m16 > row)      ? -INFINITY : s0[r] * scale;
      const float v1 = (ks + 16 + m16 > row) ? -INFINITY : s1[r] * scale;
      p0[r] = v0; p1[r] = v1;
      tmax[r] = fmaxf(v0, v1);
    }
#pragma unroll
    for (int off = 1; off < 16; off <<= 1)
#pragma unroll
      for (int r = 0; r < 4; ++r)
        tmax[r] = fmaxf(tmax[r], __shfl_xor(tmax[r], off, 64));
    float alpha[4], rsum[4];
#pragma unroll
    for (int r = 0; r < 4; ++r) {
      const float mn = fmaxf(mrow[r], tmax[r]);
      alpha[r] = expf(mrow[r] - mn);
      mrow[r] = mn;
      const float e0 = expf(p0[r] - mn);
      const float e1 = expf(p1[r] - mn);
      p0[r] = e0; p1[r] = e1;
      rsum[r] = e0 + e1;
    }
#pragma unroll
    for (int off = 1; off < 16; off <<= 1)
#pragma unroll
      for (int r = 0; r < 4; ++r)
        rsum[r] += __shfl_xor(rsum[r], off, 64);
    const floatx4 av = {alpha[0], alpha[1], alpha[2], alpha[3]};
#pragma unroll
    for (int r = 0; r < 4; ++r) lrow[r] = lrow[r] * alpha[r] + rsum[r];
#pragma unroll
    for (int dt = 0; dt < 8; ++dt) oacc[dt] *= av;
    // P: C-layout -> A-layout via wave-private LDS (bf16)
#pragma unroll
    for (int r = 0; r < 4; ++r) {
      Pw[(quad * 4 + r) * 40 + m16]      = cvt1(p0[r]);
      Pw[(quad * 4 + r) * 40 + 16 + m16] = cvt1(p1[r]);
    }
    const short8 pa = *reinterpret_cast<const short8*>(&Pw[m16 * 40 + quad * 8]);
#pragma unroll
    for (int dt = 0; dt < 8; ++dt) {
      short8 vfr = *reinterpret_cast<const short8*>(Vtp + (size_t)(dt * 16 + m16) * S_LEN + ks + quad * 8);
      oacc[dt] = __builtin_amdgcn_mfma_f32_16x16x32_bf16(pa, vfr, oacc[dt], 0, 0, 0);
    }
  }

  float invl[4];
#pragma unroll
  for (int r = 0; r < 4; ++r) invl[r] = 1.0f / lrow[r];
  // aout layout [b, s, h, d] => row-major (B*S) x HID matrix for the out-proj
  bf16* op = aout + (((size_t)b * S_LEN + myrow) * NHEADS + h) * HDIM + m16;
#pragma unroll
  for (int dt = 0; dt < 8; ++dt)
#pragma unroll
    for (int r = 0; r < 4; ++r)
      op[(size_t)r * NHEADS * HDIM + dt * 16] = __float2bfloat16(oacc[dt][r] * invl[r]);
}

extern "C" void kernel_launch(void* const* d_in, const int* in_sizes, int n_in,
                              void* d_out, int out_size, void* d_ws, size_t ws_size,
                              hipStream_t stream) {
  const float* hidden_f = (const float*)d_in[0];   // [B,S,HID] fp32
  const float* wqkv_f   = (const float*)d_in[1];   // [3072,2048] fp32
  const float* wout_f   = (const float*)d_in[2];   // [2048,2048] fp32
  // d_in[3] attention_mask: pure causal, applied analytically. d_in[4] position_ids: arange.
  float* out = (float*)d_out;                       // [B,S,HID] fp32

  char* ws = (char*)d_ws;
  size_t off = 0;
  bf16* hbf    = (bf16*)(ws + off); off += 16777216;   // [4096,2048] bf16
  bf16* wqkvbf = (bf16*)(ws + off); off += 12582912;   // [3072,2048] bf16
  bf16* woutbf = (bf16*)(ws + off); off += 8388608;    // [2048,2048] bf16
  bf16* qbuf   = (bf16*)(ws + off); off += 16777216;   // [B,NH,S,HD]
  bf16* kbuf   = (bf16*)(ws + off); off += 4194304;    // [B,NKV,S,HD]
  bf16* vtbuf  = (bf16*)(ws + off); off += 4194304;    // [B,NKV,HD,S]
  bf16* abuf   = (bf16*)(ws + off); off += 16777216;   // [B,S,NH,HD]

  // 0) fp32 -> bf16 input conversion
  cvt_f32_bf16<<<4096, 256, 0, stream>>>(hidden_f, (unsigned short*)hbf,    1048576);
  cvt_f32_bf16<<<3072, 256, 0, stream>>>(wqkv_f,   (unsigned short*)wqkvbf,  786432);
  cvt_f32_bf16<<<2048, 256, 0, stream>>>(wout_f,   (unsigned short*)woutbf,  524288);

  // 1) QKV projection (+ V transposed on the way out)
  gemm_bt<0><<<dim3(24, 32), 256, 0, stream>>>(hbf, wqkvbf, 4096, 3072, 2048,
                                               qbuf, kbuf, vtbuf, nullptr);
  // 2) RoPE in place on Q and K
  rope_kernel<<<20480, 256, 0, stream>>>(qbuf, kbuf);
  // 3) causal GQA flash attention
  attn_kernel<<<dim3(32, 16, 2), 256, 0, stream>>>(qbuf, kbuf, vtbuf, abuf);
  // 4) output projection (fp32 out)
  gemm_bt<1><<<dim3(16, 32), 256, 0, stream>>>(abuf, woutbf, 4096, 2048, 2048,
                                               nullptr, nullptr, nullptr, out);
}

// Round 3
// 410.521 us; speedup vs baseline: 1.9072x; 1.9072x over previous
//
#include <hip/hip_runtime.h>
#include <hip/hip_bf16.h>
#include <math.h>

#define S_LEN   2048
#define HIDDEN  2048
#define NHEADS  16
#define NKVH    4
#define HDIM    128

typedef short  short8  __attribute__((ext_vector_type(8)));
typedef float  floatx4 __attribute__((ext_vector_type(4)));
typedef __hip_bfloat16 bf16;

__device__ inline void async_copy16(const void* g, void* l) {
  __builtin_amdgcn_global_load_lds((__attribute__((address_space(1))) void*)(g),
                                   (__attribute__((address_space(3))) void*)(l),
                                   16, 0, 0);
}

__device__ inline unsigned short cvt1(float x) {
  bf16 t = __float2bfloat16(x);
  return *reinterpret_cast<unsigned short*>(&t);
}
__device__ inline float us2f(unsigned short u) {
  unsigned int v = ((unsigned int)u) << 16;
  return *reinterpret_cast<float*>(&v);
}

// fp32 -> bf16, 8 elements per thread
__global__ __launch_bounds__(256) void cvt_f32_bf16(const float* __restrict__ src,
                                                    unsigned short* __restrict__ dst,
                                                    int n8) {
  const int i = blockIdx.x * 256 + threadIdx.x;
  if (i >= n8) return;
  const float4 a = reinterpret_cast<const float4*>(src)[i * 2];
  const float4 b = reinterpret_cast<const float4*>(src)[i * 2 + 1];
  unsigned short o[8] = {cvt1(a.x), cvt1(a.y), cvt1(a.z), cvt1(a.w),
                         cvt1(b.x), cvt1(b.y), cvt1(b.z), cvt1(b.w)};
  *reinterpret_cast<short8*>(dst + (size_t)i * 8) = *reinterpret_cast<short8*>(o);
}

// C[M,N] = A[M,K] * B[N,K]^T, bf16 in, fp32 accumulate.
template<int MODE>
__global__ __launch_bounds__(256) void gemm_bt(const bf16* __restrict__ A,
                                               const bf16* __restrict__ B,
                                               int M, int N, int K,
                                               bf16* __restrict__ qbuf,
                                               bf16* __restrict__ kbuf,
                                               bf16* __restrict__ vtbuf,
                                               float* __restrict__ Cout)
{
  __shared__ unsigned short As[128 * 32];
  __shared__ unsigned short Bs[128 * 32];
  const int t    = threadIdx.x;
  const int w    = t >> 6;
  const int lane = t & 63;
  const int m16  = lane & 15;
  const int quad = lane >> 4;
  const int wm   = (w >> 1) * 64;
  const int wn   = (w & 1) * 64;
  const int bm   = blockIdx.y, bn = blockIdx.x;

  const floatx4 zf = {0.f, 0.f, 0.f, 0.f};
  floatx4 acc[4][4];
#pragma unroll
  for (int i = 0; i < 4; ++i)
#pragma unroll
    for (int j = 0; j < 4; ++j) acc[i][j] = zf;

  const bf16* gA = A + (size_t)(bm * 128 + (t >> 2)) * K + (t & 3) * 8;
  const bf16* gB = B + (size_t)(bn * 128 + (t >> 2)) * K + (t & 3) * 8;
  unsigned short* lA = &As[w * 512];
  unsigned short* lB = &Bs[w * 512];

  for (int k0 = 0; k0 < K; k0 += 32) {
    __syncthreads();
#pragma unroll
    for (int i = 0; i < 2; ++i) {
      async_copy16(gA + (size_t)(64 * i) * K + k0, lA + i * 2048);
      async_copy16(gB + (size_t)(64 * i) * K + k0, lB + i * 2048);
    }
    __builtin_amdgcn_s_waitcnt(0);
    __syncthreads();
    short8 af[4], bfr[4];
#pragma unroll
    for (int mi = 0; mi < 4; ++mi)
      af[mi] = *reinterpret_cast<const short8*>(&As[(wm + mi * 16 + m16) * 32 + quad * 8]);
#pragma unroll
    for (int ni = 0; ni < 4; ++ni)
      bfr[ni] = *reinterpret_cast<const short8*>(&Bs[(wn + ni * 16 + m16) * 32 + quad * 8]);
#pragma unroll
    for (int mi = 0; mi < 4; ++mi)
#pragma unroll
      for (int ni = 0; ni < 4; ++ni)
        acc[mi][ni] = __builtin_amdgcn_mfma_f32_16x16x32_bf16(af[mi], bfr[ni], acc[mi][ni], 0, 0, 0);
  }

#pragma unroll
  for (int mi = 0; mi < 4; ++mi)
#pragma unroll
    for (int ni = 0; ni < 4; ++ni) {
      const int row0 = bm * 128 + wm + mi * 16 + quad * 4;
      const int col  = bn * 128 + wn + ni * 16 + m16;
#pragma unroll
      for (int r = 0; r < 4; ++r) {
        const float v = acc[mi][ni][r];
        const int m = row0 + r;
        if (MODE == 0) {
          const int b = m >> 11, s = m & 2047;
          if (col < HIDDEN) {
            const int hh = col >> 7, d = col & 127;
            qbuf[(((size_t)(b * NHEADS + hh)) * S_LEN + s) * HDIM + d] = __float2bfloat16(v);
          } else if (col < HIDDEN + NKVH * HDIM) {
            const int nn = col - HIDDEN; const int hh = nn >> 7, d = nn & 127;
            kbuf[(((size_t)(b * NKVH + hh)) * S_LEN + s) * HDIM + d] = __float2bfloat16(v);
          } else {
            const int nn = col - HIDDEN - NKVH * HDIM; const int hh = nn >> 7, d = nn & 127;
            vtbuf[(((size_t)(b * NKVH + hh)) * HDIM + d) * S_LEN + s] = __float2bfloat16(v);
          }
        } else {
          Cout[(size_t)m * N + col] = v;
        }
      }
    }
}

// In-place RoPE on qbuf and kbuf; pos == s. Q additionally pre-scaled by 1/sqrt(HD).
__global__ __launch_bounds__(256) void rope_kernel(bf16* __restrict__ qbuf,
                                                   bf16* __restrict__ kbuf)
{
  const int idx = blockIdx.x * 256 + threadIdx.x;
  const int QC = 2 * NHEADS * S_LEN * 64;  // 4,194,304
  bf16* base; int s, j; float post;
  if (idx < QC) {
    j = idx & 63; const int tt = idx >> 6; s = tt & (S_LEN - 1);
    base = qbuf + (size_t)tt * HDIM;
    post = 0.08838834764831845f;           // fold softmax scale into Q
  } else {
    const int k = idx - QC;
    j = k & 63; const int tt = k >> 6; s = tt & (S_LEN - 1);
    base = kbuf + (size_t)tt * HDIM;
    post = 1.0f;
  }
  const float inv = 1.0f / powf(10000.0f, (float)j * (1.0f / 64.0f));
  const float ang = (float)s * inv;
  const float c = cosf(ang), sn = sinf(ang);
  const float x0 = __bfloat162float(base[j]);
  const float x1 = __bfloat162float(base[j + 64]);
  base[j]      = __float2bfloat16((x0 * c - x1 * sn) * post);
  base[j + 64] = __float2bfloat16((x1 * c + x0 * sn) * post);
}

// ---------------- Attention phase A: split-K partials, max-free softmax ------
// Block = (q-tile i, k-chunk c, kvh, b). 4 waves = the 4 q-heads sharing kvh.
// K/V tiles staged in LDS via global_load_lds with XOR swizzle (2-way = free).
// Each wave: 16 q rows; partial num (bf16) + row-sums l (fp32) written to ws.
__global__ __launch_bounds__(256) void attn_partial(const bf16* __restrict__ qbuf,
                                                    const bf16* __restrict__ kbuf,
                                                    const bf16* __restrict__ vtbuf,
                                                    unsigned short* __restrict__ pnum,
                                                    float* __restrict__ plsum)
{
  __shared__ unsigned short Ks[4096];   // 32 keys x 128d, swizzled 16B chunks
  __shared__ unsigned short Vs[4096];   // 128d x 32 keys, swizzled 16B chunks
  __shared__ unsigned short Ps[4][640]; // per-wave P transpose, stride 40
  const int i = blockIdx.x >> 1, c = blockIdx.x & 1;
  const int len = (i >> 1) + 1;                 // # of 32-key iterations needed
  const int nch = (len + 31) >> 5;              // 1 or 2 chunks
  if (c >= nch) return;
  const int kvh = blockIdx.y, b = blockIdx.z;
  const int t = threadIdx.x, w = t >> 6, lane = t & 63;
  const int m16 = lane & 15, quad = lane >> 4;
  const int h = kvh * 4 + w;

  // Q fragments (already scaled by 1/sqrt(HD))
  const bf16* Qp = qbuf + (((size_t)(b * NHEADS + h)) * S_LEN + i * 16 + m16) * HDIM;
  short8 qf[4];
#pragma unroll
  for (int cc = 0; cc < 4; ++cc)
    qf[cc] = *reinterpret_cast<const short8*>(Qp + cc * 32 + quad * 8);

  const bf16* Kp  = kbuf  + ((size_t)(b * NKVH + kvh)) * S_LEN * HDIM;
  const bf16* Vtp = vtbuf + ((size_t)(b * NKVH + kvh)) * HDIM * S_LEN;

  // staging address constants (per lane)
  const int kk = lane >> 4, cK = lane & 15;
  const int rKa = w * 8 + kk, rKb = rKa + 4;
  const int offKa = rKa * 128 + ((cK ^ (rKa & 7)) * 8);
  const int offKb = rKb * 128 + ((cK ^ (rKb & 7)) * 8);
  unsigned short* dKa = Ks + w * 1024;
  unsigned short* dKb = Ks + w * 1024 + 512;
  const int dd = lane >> 2, cV = lane & 3;
  const int dVa = w * 32 + dd, dVb = dVa + 16;
  const int offVa = dVa * 2048 + ((cV ^ ((dVa >> 1) & 3)) * 8);
  const int offVb = dVb * 2048 + ((cV ^ ((dVb >> 1) & 3)) * 8);
  unsigned short* dVp0 = Vs + w * 1024;
  unsigned short* dVp1 = Vs + w * 1024 + 512;

  const floatx4 zf = {0.f, 0.f, 0.f, 0.f};
  floatx4 oacc[8];
#pragma unroll
  for (int d = 0; d < 8; ++d) oacc[d] = zf;
  floatx4 lacc = zf;
  unsigned short ones_s[8] = {0x3F80,0x3F80,0x3F80,0x3F80,0x3F80,0x3F80,0x3F80,0x3F80};
  const short8 ones = *reinterpret_cast<short8*>(ones_s);

  unsigned short* Pw = &Ps[w][0];
  const int k0 = c * 32, k1 = (k0 + 32 < len) ? (k0 + 32) : len;
  const int myrow = i * 16 + quad * 4;

  for (int ki = k0; ki < k1; ++ki) {
    const int ks = ki * 32;
    __syncthreads();
    async_copy16(Kp + (size_t)ks * 128 + offKa, dKa);
    async_copy16(Kp + (size_t)ks * 128 + offKb, dKb);
    async_copy16(Vtp + ks + offVa, dVp0);
    async_copy16(Vtp + ks + offVb, dVp1);
    __builtin_amdgcn_s_waitcnt(0);
    __syncthreads();

    floatx4 s0 = zf, s1 = zf;
#pragma unroll
    for (int cc = 0; cc < 4; ++cc) {
      const int sw = ((cc * 4 + quad) ^ (m16 & 7)) * 8;
      short8 kf0 = *reinterpret_cast<const short8*>(&Ks[m16 * 128 + sw]);
      short8 kf1 = *reinterpret_cast<const short8*>(&Ks[(16 + m16) * 128 + sw]);
      s0 = __builtin_amdgcn_mfma_f32_16x16x32_bf16(qf[cc], kf0, s0, 0, 0, 0);
      s1 = __builtin_amdgcn_mfma_f32_16x16x32_bf16(qf[cc], kf1, s1, 0, 0, 0);
    }
    // max-free softmax numerator: p = exp(s), masked -> 0
#pragma unroll
    for (int r = 0; r < 4; ++r) {
      const int row = myrow + r;
      const float p0 = (ks + m16      > row) ? 0.f : __expf(s0[r]);
      const float p1 = (ks + 16 + m16 > row) ? 0.f : __expf(s1[r]);
      Pw[(quad * 4 + r) * 40 + m16]      = cvt1(p0);
      Pw[(quad * 4 + r) * 40 + 16 + m16] = cvt1(p1);
    }
    const short8 pa = *reinterpret_cast<const short8*>(&Pw[m16 * 40 + quad * 8]);
    lacc = __builtin_amdgcn_mfma_f32_16x16x32_bf16(pa, ones, lacc, 0, 0, 0);
#pragma unroll
    for (int dt = 0; dt < 8; ++dt) {
      short8 vfr = *reinterpret_cast<const short8*>(
          &Vs[(dt * 16 + m16) * 32 + ((quad ^ ((m16 >> 1) & 3)) * 8)]);
      oacc[dt] = __builtin_amdgcn_mfma_f32_16x16x32_bf16(pa, vfr, oacc[dt], 0, 0, 0);
    }
  }

  // partial slot (compact triangle indexing, 192 per (b,h))
  const int a = i >> 1, g = a >> 5;
  const int base = 2 * (a + (a & 31) * g) + (i & 1) * (g + 1);
  const int slot = (b * NHEADS + h) * 192 + base + c;
  unsigned short* np = pnum + (size_t)slot * 2048;
#pragma unroll
  for (int dt = 0; dt < 8; ++dt)
#pragma unroll
    for (int r = 0; r < 4; ++r)
      np[(quad * 4 + r) * 128 + dt * 16 + m16] = cvt1(oacc[dt][r]);
  if (m16 == 0) {
#pragma unroll
    for (int r = 0; r < 4; ++r)
      plsum[slot * 16 + quad * 4 + r] = lacc[r];
  }
}

// ---------------- Attention phase B: combine partials, divide, write abuf ----
__global__ __launch_bounds__(256) void attn_combine(const unsigned short* __restrict__ pnum,
                                                    const float* __restrict__ plsum,
                                                    bf16* __restrict__ abuf)
{
  const int i = blockIdx.x, h = blockIdx.y, b = blockIdx.z;
  const int t = threadIdx.x, row = t >> 4, c0 = (t & 15) * 8;
  const int a = i >> 1, g = a >> 5;
  const int base = 2 * (a + (a & 31) * g) + (i & 1) * (g + 1);
  const int nch = g + 1;
  const int hb = (b * NHEADS + h) * 192 + base;
  float acc[8] = {0.f,0.f,0.f,0.f,0.f,0.f,0.f,0.f};
  float lsum = 0.f;
  for (int c = 0; c < nch; ++c) {
    const unsigned short* np = pnum + (size_t)(hb + c) * 2048 + row * 128 + c0;
    const short8 v = *reinterpret_cast<const short8*>(np);
#pragma unroll
    for (int j = 0; j < 8; ++j) acc[j] += us2f(((unsigned short*)&v)[j]);
    lsum += plsum[(hb + c) * 16 + row];
  }
  const float invl = 1.0f / lsum;
  unsigned short o[8];
#pragma unroll
  for (int j = 0; j < 8; ++j) o[j] = cvt1(acc[j] * invl);
  *reinterpret_cast<short8*>(abuf + (((size_t)b * S_LEN + i * 16 + row) * NHEADS + h) * HDIM + c0)
      = *reinterpret_cast<short8*>(o);
}

extern "C" void kernel_launch(void* const* d_in, const int* in_sizes, int n_in,
                              void* d_out, int out_size, void* d_ws, size_t ws_size,
                              hipStream_t stream) {
  const float* hidden_f = (const float*)d_in[0];
  const float* wqkv_f   = (const float*)d_in[1];
  const float* wout_f   = (const float*)d_in[2];
  float* out = (float*)d_out;

  char* ws = (char*)d_ws;
  bf16* hbf    = (bf16*)(ws);                    // [4096,2048]   (dead after gemm0)
  bf16* wqkvbf = (bf16*)(ws + 16777216);         // [3072,2048]   (dead after gemm0)
  bf16* woutbf = (bf16*)(ws + 29360128);         // [2048,2048]
  bf16* qbuf   = (bf16*)(ws + 37748736);         // [B,NH,S,HD]
  bf16* kbuf   = (bf16*)(ws + 54525952);         // [B,NKV,S,HD]
  bf16* vtbuf  = (bf16*)(ws + 58720256);         // [B,NKV,HD,S]
  bf16* abuf   = (bf16*)(ws + 62914560);         // [B,S,NH,HD]
  // partials overlay the dead hbf/wqkvbf region (25.2 MB < 29.4 MB)
  unsigned short* pnum = (unsigned short*)(ws);  // 6144 slots x 16x128 bf16
  float* plsum = (float*)(ws + 79691776);        // 6144 x 16 fp32

  cvt_f32_bf16<<<4096, 256, 0, stream>>>(hidden_f, (unsigned short*)hbf,    1048576);
  cvt_f32_bf16<<<3072, 256, 0, stream>>>(wqkv_f,   (unsigned short*)wqkvbf,  786432);
  cvt_f32_bf16<<<2048, 256, 0, stream>>>(wout_f,   (unsigned short*)woutbf,  524288);

  gemm_bt<0><<<dim3(24, 32), 256, 0, stream>>>(hbf, wqkvbf, 4096, 3072, 2048,
                                               qbuf, kbuf, vtbuf, nullptr);
  rope_kernel<<<20480, 256, 0, stream>>>(qbuf, kbuf);
  attn_partial<<<dim3(256, 4, 2), 256, 0, stream>>>(qbuf, kbuf, vtbuf, pnum, plsum);
  attn_combine<<<dim3(128, 16, 2), 256, 0, stream>>>(pnum, plsum, abuf);
  gemm_bt<1><<<dim3(16, 32), 256, 0, stream>>>(abuf, woutbf, 4096, 2048, 2048,
                                               nullptr, nullptr, nullptr, out);
}

// Round 4
// 362.819 us; speedup vs baseline: 2.1579x; 1.1315x over previous
//
#include <hip/hip_runtime.h>
#include <hip/hip_bf16.h>
#include <math.h>

#define S_LEN   2048
#define HIDDEN  2048
#define NHEADS  16
#define NKVH    4
#define HDIM    128

typedef short  short8  __attribute__((ext_vector_type(8)));
typedef float  floatx4 __attribute__((ext_vector_type(4)));
typedef __hip_bfloat16 bf16;

__device__ inline void async_copy16(const void* g, void* l) {
  __builtin_amdgcn_global_load_lds((__attribute__((address_space(1))) void*)(g),
                                   (__attribute__((address_space(3))) void*)(l),
                                   16, 0, 0);
}

__device__ inline unsigned short cvt1(float x) {
  bf16 t = __float2bfloat16(x);
  return *reinterpret_cast<unsigned short*>(&t);
}
__device__ inline float us2f(unsigned short u) {
  unsigned int v = ((unsigned int)u) << 16;
  return *reinterpret_cast<float*>(&v);
}

// fp32 -> bf16 for all three inputs in one launch; dst regions contiguous.
#define N8_H  1048576
#define N8_WQ  786432
#define N8_WO  524288
__global__ __launch_bounds__(256) void cvt_all(const float* __restrict__ h,
                                               const float* __restrict__ wq,
                                               const float* __restrict__ wo,
                                               unsigned short* __restrict__ dst) {
  const int i = blockIdx.x * 256 + threadIdx.x;
  if (i >= N8_H + N8_WQ + N8_WO) return;
  const float* src; int j;
  if (i < N8_H)              { src = h;  j = i; }
  else if (i < N8_H + N8_WQ) { src = wq; j = i - N8_H; }
  else                       { src = wo; j = i - N8_H - N8_WQ; }
  const float4 a = reinterpret_cast<const float4*>(src)[j * 2];
  const float4 b = reinterpret_cast<const float4*>(src)[j * 2 + 1];
  unsigned short o[8] = {cvt1(a.x), cvt1(a.y), cvt1(a.z), cvt1(a.w),
                         cvt1(b.x), cvt1(b.y), cvt1(b.z), cvt1(b.w)};
  *reinterpret_cast<short8*>(dst + (size_t)i * 8) = *reinterpret_cast<short8*>(o);
}

// C[M,N] = A[M,K] * B[N,K]^T, bf16 in, fp32 accumulate.
template<int MODE>
__global__ __launch_bounds__(256) void gemm_bt(const bf16* __restrict__ A,
                                               const bf16* __restrict__ B,
                                               int M, int N, int K,
                                               bf16* __restrict__ qbuf,
                                               bf16* __restrict__ kbuf,
                                               bf16* __restrict__ vtbuf,
                                               float* __restrict__ Cout)
{
  __shared__ unsigned short As[128 * 32];
  __shared__ unsigned short Bs[128 * 32];
  const int t    = threadIdx.x;
  const int w    = t >> 6;
  const int lane = t & 63;
  const int m16  = lane & 15;
  const int quad = lane >> 4;
  const int wm   = (w >> 1) * 64;
  const int wn   = (w & 1) * 64;
  const int bm   = blockIdx.y, bn = blockIdx.x;

  const floatx4 zf = {0.f, 0.f, 0.f, 0.f};
  floatx4 acc[4][4];
#pragma unroll
  for (int i = 0; i < 4; ++i)
#pragma unroll
    for (int j = 0; j < 4; ++j) acc[i][j] = zf;

  const bf16* gA = A + (size_t)(bm * 128 + (t >> 2)) * K + (t & 3) * 8;
  const bf16* gB = B + (size_t)(bn * 128 + (t >> 2)) * K + (t & 3) * 8;
  unsigned short* lA = &As[w * 512];
  unsigned short* lB = &Bs[w * 512];

  for (int k0 = 0; k0 < K; k0 += 32) {
    __syncthreads();
#pragma unroll
    for (int i = 0; i < 2; ++i) {
      async_copy16(gA + (size_t)(64 * i) * K + k0, lA + i * 2048);
      async_copy16(gB + (size_t)(64 * i) * K + k0, lB + i * 2048);
    }
    __builtin_amdgcn_s_waitcnt(0);
    __syncthreads();
    short8 af[4], bfr[4];
#pragma unroll
    for (int mi = 0; mi < 4; ++mi)
      af[mi] = *reinterpret_cast<const short8*>(&As[(wm + mi * 16 + m16) * 32 + quad * 8]);
#pragma unroll
    for (int ni = 0; ni < 4; ++ni)
      bfr[ni] = *reinterpret_cast<const short8*>(&Bs[(wn + ni * 16 + m16) * 32 + quad * 8]);
#pragma unroll
    for (int mi = 0; mi < 4; ++mi)
#pragma unroll
      for (int ni = 0; ni < 4; ++ni)
        acc[mi][ni] = __builtin_amdgcn_mfma_f32_16x16x32_bf16(af[mi], bfr[ni], acc[mi][ni], 0, 0, 0);
  }

#pragma unroll
  for (int mi = 0; mi < 4; ++mi)
#pragma unroll
    for (int ni = 0; ni < 4; ++ni) {
      const int row0 = bm * 128 + wm + mi * 16 + quad * 4;
      const int col  = bn * 128 + wn + ni * 16 + m16;
#pragma unroll
      for (int r = 0; r < 4; ++r) {
        const float v = acc[mi][ni][r];
        const int m = row0 + r;
        if (MODE == 0) {
          const int b = m >> 11, s = m & 2047;
          if (col < HIDDEN) {
            const int hh = col >> 7, d = col & 127;
            qbuf[(((size_t)(b * NHEADS + hh)) * S_LEN + s) * HDIM + d] = __float2bfloat16(v);
          } else if (col < HIDDEN + NKVH * HDIM) {
            const int nn = col - HIDDEN; const int hh = nn >> 7, d = nn & 127;
            kbuf[(((size_t)(b * NKVH + hh)) * S_LEN + s) * HDIM + d] = __float2bfloat16(v);
          } else {
            const int nn = col - HIDDEN - NKVH * HDIM; const int hh = nn >> 7, d = nn & 127;
            vtbuf[(((size_t)(b * NKVH + hh)) * HDIM + d) * S_LEN + s] = __float2bfloat16(v);
          }
        } else {
          Cout[(size_t)m * N + col] = v;
        }
      }
    }
}

// In-place RoPE on qbuf and kbuf; pos == s. Q additionally pre-scaled by 1/sqrt(HD).
__global__ __launch_bounds__(256) void rope_kernel(bf16* __restrict__ qbuf,
                                                   bf16* __restrict__ kbuf)
{
  const int idx = blockIdx.x * 256 + threadIdx.x;
  const int QC = 2 * NHEADS * S_LEN * 64;  // 4,194,304
  bf16* base; int s, j; float post;
  if (idx < QC) {
    j = idx & 63; const int tt = idx >> 6; s = tt & (S_LEN - 1);
    base = qbuf + (size_t)tt * HDIM;
    post = 0.08838834764831845f;           // fold softmax scale into Q
  } else {
    const int k = idx - QC;
    j = k & 63; const int tt = k >> 6; s = tt & (S_LEN - 1);
    base = kbuf + (size_t)tt * HDIM;
    post = 1.0f;
  }
  // inv_freq = 10000^(-j/64) = 2^(-j*log2(10000)/64)
  const float inv = exp2f((float)j * -0.2076205059f);
  const float ang = (float)s * inv;
  float sn, c;
  __sincosf(ang, &sn, &c);
  const float x0 = __bfloat162float(base[j]);
  const float x1 = __bfloat162float(base[j + 64]);
  base[j]      = __float2bfloat16((x0 * c - x1 * sn) * post);
  base[j + 64] = __float2bfloat16((x1 * c + x0 * sn) * post);
}

// ---------------- Attention phase A: split-K partials, max-free softmax ------
// Block = (q-tile i, k-chunk c, kvh, b). 4 waves = the 4 q-heads sharing kvh.
// K/V tiles double-buffered in LDS: prefetch tile ki+1 while computing on ki;
// ONE barrier per iteration, whose vmcnt(0) drain overlaps the compute phase.
__global__ __launch_bounds__(256) void attn_partial(const bf16* __restrict__ qbuf,
                                                    const bf16* __restrict__ kbuf,
                                                    const bf16* __restrict__ vtbuf,
                                                    unsigned short* __restrict__ pnum,
                                                    float* __restrict__ plsum)
{
  __shared__ unsigned short Ks[2][4096];  // 32 keys x 128d, swizzled 16B chunks
  __shared__ unsigned short Vs[2][4096];  // 128d x 32 keys, swizzled 16B chunks
  __shared__ unsigned short Ps[4][640];   // per-wave P transpose, stride 40
  const int i = blockIdx.x >> 1, c = blockIdx.x & 1;
  const int len = (i >> 1) + 1;                 // # of 32-key iterations needed
  const int nch = (len + 31) >> 5;              // 1 or 2 chunks
  if (c >= nch) return;
  const int half = (len + 1) >> 1;              // balanced split for nch=2
  const int k0 = (nch == 1) ? 0   : (c ? half : 0);
  const int k1 = (nch == 1) ? len : (c ? len  : half);
  const int kvh = blockIdx.y, b = blockIdx.z;
  const int t = threadIdx.x, w = t >> 6, lane = t & 63;
  const int m16 = lane & 15, quad = lane >> 4;
  const int h = kvh * 4 + w;

  // Q fragments (already scaled by 1/sqrt(HD))
  const bf16* Qp = qbuf + (((size_t)(b * NHEADS + h)) * S_LEN + i * 16 + m16) * HDIM;
  short8 qf[4];
#pragma unroll
  for (int cc = 0; cc < 4; ++cc)
    qf[cc] = *reinterpret_cast<const short8*>(Qp + cc * 32 + quad * 8);

  const bf16* Kp  = kbuf  + ((size_t)(b * NKVH + kvh)) * S_LEN * HDIM;
  const bf16* Vtp = vtbuf + ((size_t)(b * NKVH + kvh)) * HDIM * S_LEN;

  // staging address constants (per lane)
  const int kk = lane >> 4, cK = lane & 15;
  const int rKa = w * 8 + kk, rKb = rKa + 4;
  const int offKa = rKa * 128 + ((cK ^ (rKa & 7)) * 8);
  const int offKb = rKb * 128 + ((cK ^ (rKb & 7)) * 8);
  const int dd = lane >> 2, cV = lane & 3;
  const int dVa = w * 32 + dd, dVb = dVa + 16;
  const int offVa = dVa * 2048 + ((cV ^ ((dVa >> 1) & 3)) * 8);
  const int offVb = dVb * 2048 + ((cV ^ ((dVb >> 1) & 3)) * 8);

  const floatx4 zf = {0.f, 0.f, 0.f, 0.f};
  floatx4 oacc[8];
#pragma unroll
  for (int d = 0; d < 8; ++d) oacc[d] = zf;
  floatx4 lacc = zf;
  unsigned short ones_s[8] = {0x3F80,0x3F80,0x3F80,0x3F80,0x3F80,0x3F80,0x3F80,0x3F80};
  const short8 ones = *reinterpret_cast<short8*>(ones_s);

  unsigned short* Pw = &Ps[w][0];
  const int myrow = i * 16 + quad * 4;

  // prologue: stage first tile into buffer 0
  {
    const int ks = k0 * 32;
    async_copy16(Kp + (size_t)ks * 128 + offKa, &Ks[0][w * 1024]);
    async_copy16(Kp + (size_t)ks * 128 + offKb, &Ks[0][w * 1024 + 512]);
    async_copy16(Vtp + ks + offVa, &Vs[0][w * 1024]);
    async_copy16(Vtp + ks + offVb, &Vs[0][w * 1024 + 512]);
  }
  __syncthreads();

  for (int ki = k0; ki < k1; ++ki) {
    const int buf = (ki - k0) & 1;
    if (ki + 1 < k1) {   // prefetch next tile into the other buffer
      const int ks = (ki + 1) * 32;
      async_copy16(Kp + (size_t)ks * 128 + offKa, &Ks[buf ^ 1][w * 1024]);
      async_copy16(Kp + (size_t)ks * 128 + offKb, &Ks[buf ^ 1][w * 1024 + 512]);
      async_copy16(Vtp + ks + offVa, &Vs[buf ^ 1][w * 1024]);
      async_copy16(Vtp + ks + offVb, &Vs[buf ^ 1][w * 1024 + 512]);
    }
    const int ks = ki * 32;
    floatx4 s0 = zf, s1 = zf;
#pragma unroll
    for (int cc = 0; cc < 4; ++cc) {
      const int sw = ((cc * 4 + quad) ^ (m16 & 7)) * 8;
      short8 kf0 = *reinterpret_cast<const short8*>(&Ks[buf][m16 * 128 + sw]);
      short8 kf1 = *reinterpret_cast<const short8*>(&Ks[buf][(16 + m16) * 128 + sw]);
      s0 = __builtin_amdgcn_mfma_f32_16x16x32_bf16(qf[cc], kf0, s0, 0, 0, 0);
      s1 = __builtin_amdgcn_mfma_f32_16x16x32_bf16(qf[cc], kf1, s1, 0, 0, 0);
    }
    // max-free softmax numerator: p = exp(s), masked -> 0
#pragma unroll
    for (int r = 0; r < 4; ++r) {
      const int row = myrow + r;
      const float p0 = (ks + m16      > row) ? 0.f : __expf(s0[r]);
      const float p1 = (ks + 16 + m16 > row) ? 0.f : __expf(s1[r]);
      Pw[(quad * 4 + r) * 40 + m16]      = cvt1(p0);
      Pw[(quad * 4 + r) * 40 + 16 + m16] = cvt1(p1);
    }
    const short8 pa = *reinterpret_cast<const short8*>(&Pw[m16 * 40 + quad * 8]);
    lacc = __builtin_amdgcn_mfma_f32_16x16x32_bf16(pa, ones, lacc, 0, 0, 0);
#pragma unroll
    for (int dt = 0; dt < 8; ++dt) {
      short8 vfr = *reinterpret_cast<const short8*>(
          &Vs[buf][(dt * 16 + m16) * 32 + ((quad ^ ((m16 >> 1) & 3)) * 8)]);
      oacc[dt] = __builtin_amdgcn_mfma_f32_16x16x32_bf16(pa, vfr, oacc[dt], 0, 0, 0);
    }
    __syncthreads();   // drains prefetch vmcnt + all waves' LDS reads
  }

  // partial slot (compact triangle indexing, 192 per (b,h))
  const int a = i >> 1, g = a >> 5;
  const int base = 2 * (a + (a & 31) * g) + (i & 1) * (g + 1);
  const int slot = (b * NHEADS + h) * 192 + base + c;
  unsigned short* np = pnum + (size_t)slot * 2048;
#pragma unroll
  for (int dt = 0; dt < 8; ++dt)
#pragma unroll
    for (int r = 0; r < 4; ++r)
      np[(quad * 4 + r) * 128 + dt * 16 + m16] = cvt1(oacc[dt][r]);
  if (m16 == 0) {
#pragma unroll
    for (int r = 0; r < 4; ++r)
      plsum[slot * 16 + quad * 4 + r] = lacc[r];
  }
}

// ---------------- Attention phase B: combine partials, divide, write abuf ----
__global__ __launch_bounds__(256) void attn_combine(const unsigned short* __restrict__ pnum,
                                                    const float* __restrict__ plsum,
                                                    bf16* __restrict__ abuf)
{
  const int i = blockIdx.x, h = blockIdx.y, b = blockIdx.z;
  const int t = threadIdx.x, row = t >> 4, c0 = (t & 15) * 8;
  const int a = i >> 1, g = a >> 5;
  const int base = 2 * (a + (a & 31) * g) + (i & 1) * (g + 1);
  const int nch = g + 1;
  const int hb = (b * NHEADS + h) * 192 + base;
  float acc[8] = {0.f,0.f,0.f,0.f,0.f,0.f,0.f,0.f};
  float lsum = 0.f;
  for (int c = 0; c < nch; ++c) {
    const unsigned short* np = pnum + (size_t)(hb + c) * 2048 + row * 128 + c0;
    const short8 v = *reinterpret_cast<const short8*>(np);
#pragma unroll
    for (int j = 0; j < 8; ++j) acc[j] += us2f(((unsigned short*)&v)[j]);
    lsum += plsum[(hb + c) * 16 + row];
  }
  const float invl = 1.0f / lsum;
  unsigned short o[8];
#pragma unroll
  for (int j = 0; j < 8; ++j) o[j] = cvt1(acc[j] * invl);
  *reinterpret_cast<short8*>(abuf + (((size_t)b * S_LEN + i * 16 + row) * NHEADS + h) * HDIM + c0)
      = *reinterpret_cast<short8*>(o);
}

extern "C" void kernel_launch(void* const* d_in, const int* in_sizes, int n_in,
                              void* d_out, int out_size, void* d_ws, size_t ws_size,
                              hipStream_t stream) {
  const float* hidden_f = (const float*)d_in[0];
  const float* wqkv_f   = (const float*)d_in[1];
  const float* wout_f   = (const float*)d_in[2];
  float* out = (float*)d_out;

  char* ws = (char*)d_ws;
  bf16* hbf    = (bf16*)(ws);                    // [4096,2048]   (dead after gemm0)
  bf16* wqkvbf = (bf16*)(ws + 16777216);         // [3072,2048]   (dead after gemm0)
  bf16* woutbf = (bf16*)(ws + 29360128);         // [2048,2048]
  bf16* qbuf   = (bf16*)(ws + 37748736);         // [B,NH,S,HD]
  bf16* kbuf   = (bf16*)(ws + 54525952);         // [B,NKV,S,HD]
  bf16* vtbuf  = (bf16*)(ws + 58720256);         // [B,NKV,HD,S]
  bf16* abuf   = (bf16*)(ws + 62914560);         // [B,S,NH,HD]
  // partials overlay the dead hbf/wqkvbf region (25.2 MB < 29.4 MB)
  unsigned short* pnum = (unsigned short*)(ws);  // 6144 slots x 16x128 bf16
  float* plsum = (float*)(ws + 79691776);        // 6144 x 16 fp32

  cvt_all<<<9216, 256, 0, stream>>>(hidden_f, wqkv_f, wout_f, (unsigned short*)ws);

  gemm_bt<0><<<dim3(24, 32), 256, 0, stream>>>(hbf, wqkvbf, 4096, 3072, 2048,
                                               qbuf, kbuf, vtbuf, nullptr);
  rope_kernel<<<20480, 256, 0, stream>>>(qbuf, kbuf);
  attn_partial<<<dim3(256, 4, 2), 256, 0, stream>>>(qbuf, kbuf, vtbuf, pnum, plsum);
  attn_combine<<<dim3(128, 16, 2), 256, 0, stream>>>(pnum, plsum, abuf);
  gemm_bt<1><<<dim3(16, 32), 256, 0, stream>>>(abuf, woutbf, 4096, 2048, 2048,
                                               nullptr, nullptr, nullptr, out);
}